// Round 2
// baseline (551.156 us; speedup 1.0000x reference)
//
#include <hip/hip_runtime.h>
#include <math.h>

#define N_NODES 50000
#define N_EDGES 640000
#define DIM     128
#define NGRAPH  64
#define DOUT    32
#define E_TOT   (N_EDGES + N_NODES)

// ---- degree init (self-loop => deg starts at 1) + zero pooled ----
__global__ __launch_bounds__(256) void k_init(int* __restrict__ deg, float* __restrict__ pooled) {
    int i = blockIdx.x * 256 + threadIdx.x;
    if (i < N_NODES) deg[i] = 1;
    if (i < NGRAPH * DIM) pooled[i] = 0.f;
}

__global__ __launch_bounds__(256) void k_count_deg(const int* __restrict__ dst, int* __restrict__ deg) {
    int e = blockIdx.x * 256 + threadIdx.x;
    if (e < N_EDGES) atomicAdd(&deg[dst[e]], 1);
}

// ---- exclusive scan of deg -> row_start (3 kernels) ----
__global__ __launch_bounds__(512) void k_scan_block(const int* __restrict__ deg,
                                                    int* __restrict__ row_start,
                                                    int* __restrict__ bsum) {
    __shared__ int sd[512];
    int t = threadIdx.x;
    int i = blockIdx.x * 512 + t;
    int v = (i < N_NODES) ? deg[i] : 0;
    int sum = v;
    sd[t] = v; __syncthreads();
    for (int off = 1; off < 512; off <<= 1) {
        int o = (t >= off) ? sd[t - off] : 0;
        __syncthreads();
        sum += o; sd[t] = sum;
        __syncthreads();
    }
    if (i < N_NODES) row_start[i] = sum - v;       // exclusive within block
    if (t == 511) bsum[blockIdx.x] = sum;          // block total
}

__global__ __launch_bounds__(128) void k_scan_bsum(const int* __restrict__ bsum, int* __restrict__ boff) {
    __shared__ int sd[128];
    int t = threadIdx.x;
    int v = (t < 98) ? bsum[t] : 0;
    int sum = v;
    sd[t] = v; __syncthreads();
    for (int off = 1; off < 128; off <<= 1) {
        int o = (t >= off) ? sd[t - off] : 0;
        __syncthreads();
        sum += o; sd[t] = sum;
        __syncthreads();
    }
    if (t < 98) boff[t] = sum - v;                 // exclusive block offsets
}

__global__ __launch_bounds__(256) void k_finalize(const int* __restrict__ deg,
                                                  const int* __restrict__ boff,
                                                  int* __restrict__ row_start,
                                                  int* __restrict__ cursor,
                                                  float* __restrict__ dinv) {
    int i = blockIdx.x * 256 + threadIdx.x;
    if (i < N_NODES) {
        int r = row_start[i] + boff[i >> 9];
        row_start[i] = r;
        cursor[i]    = r;
        dinv[i]      = rsqrtf((float)deg[i]);
    } else if (i == N_NODES) {
        row_start[N_NODES] = E_TOT;
    }
}

// ---- CSR fill: real edges + self-loops; packed {src, norm} per edge ----
__global__ __launch_bounds__(256) void k_fill(const int* __restrict__ src, const int* __restrict__ dst,
                                              const float* __restrict__ dinv, int* __restrict__ cursor,
                                              int2* __restrict__ csr_pack) {
    int e = blockIdx.x * 256 + threadIdx.x;
    if (e < N_EDGES) {
        int s = src[e], d = dst[e];
        int pos = atomicAdd(&cursor[d], 1);
        float nw = dinv[s] * dinv[d];
        csr_pack[pos] = make_int2(s, __float_as_int(nw));
    } else if (e < E_TOT) {
        int i = e - N_EDGES;
        int pos = atomicAdd(&cursor[i], 1);
        float di = dinv[i];
        csr_pack[pos] = make_int2(i, __float_as_int(di * di));
    }
}

// ---- fp32 GEMM: Y[M,128] = X[M,128] @ W[128,128]  (no bias; bias added post-agg) ----
__global__ __launch_bounds__(256) void k_gemm(const float* __restrict__ X,
                                              const float* __restrict__ W,
                                              float* __restrict__ Y) {
    __shared__ float xs[64][DIM];
    int tid  = threadIdx.x;
    int row0 = blockIdx.x * 64;
#pragma unroll
    for (int i = 0; i < 8; ++i) {
        int idx = tid + 256 * i;          // 0..2047 float4 slots
        int r = idx >> 5, c4 = idx & 31;
        int gr = row0 + r;
        float4 v = make_float4(0.f, 0.f, 0.f, 0.f);
        if (gr < N_NODES) v = ((const float4*)(X + (size_t)gr * DIM))[c4];
        ((float4*)(&xs[r][0]))[c4] = v;
    }
    __syncthreads();
    int tx = tid & 31;     // col group: cols 4*tx..4*tx+3
    int ty = tid >> 5;     // row group: rows 8*ty..8*ty+7
    float acc[8][4] = {};
    const float4* Wp = (const float4*)W + tx;     // row k at Wp[k*32]
#pragma unroll 4
    for (int k = 0; k < DIM; ++k) {
        float4 w = Wp[k * 32];
#pragma unroll
        for (int i = 0; i < 8; ++i) {
            float xv = xs[ty * 8 + i][k];         // wave-broadcast LDS read
            acc[i][0] = fmaf(xv, w.x, acc[i][0]);
            acc[i][1] = fmaf(xv, w.y, acc[i][1]);
            acc[i][2] = fmaf(xv, w.z, acc[i][2]);
            acc[i][3] = fmaf(xv, w.w, acc[i][3]);
        }
    }
#pragma unroll
    for (int i = 0; i < 8; ++i) {
        int gr = row0 + ty * 8 + i;
        if (gr < N_NODES)
            ((float4*)(Y + (size_t)gr * DIM))[tx] =
                make_float4(acc[i][0], acc[i][1], acc[i][2], acc[i][3]);
    }
}

// ---- gather-aggregate core: half-wave (32 lanes x float4) per node, 4-deep unroll ----
// One global_load_dwordx4 fetches rows for TWO nodes (one per half-wave); 8 row-loads
// in flight per wave vs 1 in the serial version. Masked tail via w=0 / s=0.
__device__ __forceinline__ float4 agg_node(const float4* __restrict__ H4,
                                           const int2* __restrict__ pack,
                                           int e0, int e1, int lane) {
    float4 a0 = {0,0,0,0}, a1 = {0,0,0,0}, a2 = {0,0,0,0}, a3 = {0,0,0,0};
    for (int e = e0; e < e1; e += 4) {
        int2 p0 = pack[e];
        int2 p1 = (e + 1 < e1) ? pack[e + 1] : make_int2(0, 0);
        int2 p2 = (e + 2 < e1) ? pack[e + 2] : make_int2(0, 0);
        int2 p3 = (e + 3 < e1) ? pack[e + 3] : make_int2(0, 0);
        float4 v0 = H4[(size_t)p0.x * 32 + lane];
        float4 v1 = H4[(size_t)p1.x * 32 + lane];
        float4 v2 = H4[(size_t)p2.x * 32 + lane];
        float4 v3 = H4[(size_t)p3.x * 32 + lane];
        float w0 = __int_as_float(p0.y), w1 = __int_as_float(p1.y);
        float w2 = __int_as_float(p2.y), w3 = __int_as_float(p3.y);
        a0.x = fmaf(w0, v0.x, a0.x); a0.y = fmaf(w0, v0.y, a0.y);
        a0.z = fmaf(w0, v0.z, a0.z); a0.w = fmaf(w0, v0.w, a0.w);
        a1.x = fmaf(w1, v1.x, a1.x); a1.y = fmaf(w1, v1.y, a1.y);
        a1.z = fmaf(w1, v1.z, a1.z); a1.w = fmaf(w1, v1.w, a1.w);
        a2.x = fmaf(w2, v2.x, a2.x); a2.y = fmaf(w2, v2.y, a2.y);
        a2.z = fmaf(w2, v2.z, a2.z); a2.w = fmaf(w2, v2.w, a2.w);
        a3.x = fmaf(w3, v3.x, a3.x); a3.y = fmaf(w3, v3.y, a3.y);
        a3.z = fmaf(w3, v3.z, a3.z); a3.w = fmaf(w3, v3.w, a3.w);
    }
    return make_float4(a0.x + a1.x + a2.x + a3.x,
                       a0.y + a1.y + a2.y + a3.y,
                       a0.z + a1.z + a2.z + a3.z,
                       a0.w + a1.w + a2.w + a3.w);
}

// layer 1: store relu(agg + bias) to Out
__global__ __launch_bounds__(256) void k_agg_store(const float* __restrict__ H,
                                                   const int2* __restrict__ pack,
                                                   const int* __restrict__ row_start,
                                                   const float* __restrict__ bias,
                                                   float* __restrict__ Out) {
    int node = blockIdx.x * 8 + (threadIdx.x >> 5);
    int lane = threadIdx.x & 31;
    if (node >= N_NODES) return;
    int e0 = row_start[node], e1 = row_start[node + 1];
    float4 acc = agg_node((const float4*)H, pack, e0, e1, lane);
    float4 b = ((const float4*)bias)[lane];
    float4 o = make_float4(fmaxf(acc.x + b.x, 0.f), fmaxf(acc.y + b.y, 0.f),
                           fmaxf(acc.z + b.z, 0.f), fmaxf(acc.w + b.w, 0.f));
    ((float4*)Out)[(size_t)node * 32 + lane] = o;
}

// layer 2: relu(agg + bias), then atomic global-add-pool (no bufB round-trip)
__global__ __launch_bounds__(256) void k_agg_pool(const float* __restrict__ H,
                                                  const int2* __restrict__ pack,
                                                  const int* __restrict__ row_start,
                                                  const float* __restrict__ bias,
                                                  const int* __restrict__ batch,
                                                  float* __restrict__ pooled) {
    int node = blockIdx.x * 8 + (threadIdx.x >> 5);
    int lane = threadIdx.x & 63;  // unused; keep warp mapping below
    lane = threadIdx.x & 31;
    if (node >= N_NODES) return;
    int e0 = row_start[node], e1 = row_start[node + 1];
    float4 acc = agg_node((const float4*)H, pack, e0, e1, lane);
    float4 b = ((const float4*)bias)[lane];
    float4 o = make_float4(fmaxf(acc.x + b.x, 0.f), fmaxf(acc.y + b.y, 0.f),
                           fmaxf(acc.z + b.z, 0.f), fmaxf(acc.w + b.w, 0.f));
    float* dst = pooled + (size_t)batch[node] * DIM + lane * 4;
    atomicAdd(dst + 0, o.x);
    atomicAdd(dst + 1, o.y);
    atomicAdd(dst + 2, o.z);
    atomicAdd(dst + 3, o.w);
}

// ---- head: logits = pooled @ Wh + bh ; log_softmax per graph ----
__global__ __launch_bounds__(64) void k_head(const float* __restrict__ pooled,
                                             const float* __restrict__ Wh,
                                             const float* __restrict__ bh,
                                             float* __restrict__ out) {
    int g = blockIdx.x;
    int lane = threadIdx.x;
    int c = lane & 31;
    const float* p = pooled + g * DIM;
    float lg = bh[c];
#pragma unroll 8
    for (int k = 0; k < DIM; ++k) lg = fmaf(p[k], Wh[k * DOUT + c], lg);
    float m = lg;
    for (int off = 16; off >= 1; off >>= 1) m = fmaxf(m, __shfl_xor(m, off, 32));
    float ex = expf(lg - m);
    float s = ex;
    for (int off = 16; off >= 1; off >>= 1) s += __shfl_xor(s, off, 32);
    if (lane < 32) out[g * DOUT + c] = lg - m - logf(s);
}

extern "C" void kernel_launch(void* const* d_in, const int* in_sizes, int n_in,
                              void* d_out, int out_size, void* d_ws, size_t ws_size,
                              hipStream_t stream) {
    const float* x     = (const float*)d_in[0];
    const int*   ei    = (const int*)d_in[1];
    const int*   batch = (const int*)d_in[2];
    const float* W1    = (const float*)d_in[3];
    const float* b1    = (const float*)d_in[4];
    const float* W2    = (const float*)d_in[5];
    const float* b2    = (const float*)d_in[6];
    const float* Wh    = (const float*)d_in[7];
    const float* bh    = (const float*)d_in[8];
    float* out = (float*)d_out;
    const int* src = ei;
    const int* dst = ei + N_EDGES;

    char* ws = (char*)d_ws;
    size_t off = 0;
    auto alloc = [&](size_t bytes) {
        void* p = ws + off;
        off += (bytes + 255) & ~(size_t)255;
        return p;
    };
    float* bufA      = (float*)alloc((size_t)N_NODES * DIM * 4);   // 25.6 MB
    float* bufB      = (float*)alloc((size_t)N_NODES * DIM * 4);   // 25.6 MB
    int*   deg       = (int*)  alloc((size_t)N_NODES * 4);
    float* dinv      = (float*)alloc((size_t)N_NODES * 4);
    int*   row_start = (int*)  alloc((size_t)(N_NODES + 1) * 4);
    int*   cursor    = (int*)  alloc((size_t)N_NODES * 4);
    int2*  csr_pack  = (int2*) alloc((size_t)E_TOT * 8);
    float* pooled    = (float*)alloc((size_t)NGRAPH * DIM * 4);
    int*   bsum      = (int*)  alloc(128 * 4);
    int*   boff      = (int*)  alloc(128 * 4);
    (void)ws_size; (void)in_sizes; (void)n_in; (void)out_size;

    k_init      <<<(N_NODES + 255) / 256, 256, 0, stream>>>(deg, pooled);
    k_count_deg <<<(N_EDGES + 255) / 256, 256, 0, stream>>>(dst, deg);
    k_scan_block<<<98, 512, 0, stream>>>(deg, row_start, bsum);
    k_scan_bsum <<<1, 128, 0, stream>>>(bsum, boff);
    k_finalize  <<<(N_NODES + 256) / 256, 256, 0, stream>>>(deg, boff, row_start, cursor, dinv);
    k_fill      <<<(E_TOT + 255) / 256, 256, 0, stream>>>(src, dst, dinv, cursor, csr_pack);

    k_gemm    <<<(N_NODES + 63) / 64, 256, 0, stream>>>(x, W1, bufA);
    k_agg_store<<<(N_NODES + 7) / 8, 256, 0, stream>>>(bufA, csr_pack, row_start, b1, bufB);
    k_gemm    <<<(N_NODES + 63) / 64, 256, 0, stream>>>(bufB, W2, bufA);
    k_agg_pool<<<(N_NODES + 7) / 8, 256, 0, stream>>>(bufA, csr_pack, row_start, b2, batch, pooled);

    k_head<<<NGRAPH, 64, 0, stream>>>(pooled, Wh, bh, out);
}

// Round 3
// 328.285 us; speedup vs baseline: 1.6789x; 1.6789x over previous
//
#include <hip/hip_runtime.h>
#include <math.h>

#define N_NODES 50000
#define N_EDGES 640000
#define DIM     128
#define NGRAPH  64
#define DOUT    32
#define E_TOT   (N_EDGES + N_NODES)
#define POOL_CHUNK 32

// ---- degree init (self-loop => deg starts at 1) + zero pooled ----
__global__ __launch_bounds__(256) void k_init(int* __restrict__ deg, float* __restrict__ pooled) {
    int i = blockIdx.x * 256 + threadIdx.x;
    if (i < N_NODES) deg[i] = 1;
    if (i < NGRAPH * DIM) pooled[i] = 0.f;
}

__global__ __launch_bounds__(256) void k_count_deg(const int* __restrict__ dst, int* __restrict__ deg) {
    int e = blockIdx.x * 256 + threadIdx.x;
    if (e < N_EDGES) atomicAdd(&deg[dst[e]], 1);
}

// ---- exclusive scan of deg -> row_start (3 kernels) ----
__global__ __launch_bounds__(512) void k_scan_block(const int* __restrict__ deg,
                                                    int* __restrict__ row_start,
                                                    int* __restrict__ bsum) {
    __shared__ int sd[512];
    int t = threadIdx.x;
    int i = blockIdx.x * 512 + t;
    int v = (i < N_NODES) ? deg[i] : 0;
    int sum = v;
    sd[t] = v; __syncthreads();
    for (int off = 1; off < 512; off <<= 1) {
        int o = (t >= off) ? sd[t - off] : 0;
        __syncthreads();
        sum += o; sd[t] = sum;
        __syncthreads();
    }
    if (i < N_NODES) row_start[i] = sum - v;       // exclusive within block
    if (t == 511) bsum[blockIdx.x] = sum;          // block total
}

__global__ __launch_bounds__(128) void k_scan_bsum(const int* __restrict__ bsum, int* __restrict__ boff) {
    __shared__ int sd[128];
    int t = threadIdx.x;
    int v = (t < 98) ? bsum[t] : 0;
    int sum = v;
    sd[t] = v; __syncthreads();
    for (int off = 1; off < 128; off <<= 1) {
        int o = (t >= off) ? sd[t - off] : 0;
        __syncthreads();
        sum += o; sd[t] = sum;
        __syncthreads();
    }
    if (t < 98) boff[t] = sum - v;                 // exclusive block offsets
}

__global__ __launch_bounds__(256) void k_finalize(const int* __restrict__ deg,
                                                  const int* __restrict__ boff,
                                                  int* __restrict__ row_start,
                                                  int* __restrict__ cursor,
                                                  float* __restrict__ dinv) {
    int i = blockIdx.x * 256 + threadIdx.x;
    if (i < N_NODES) {
        int r = row_start[i] + boff[i >> 9];
        row_start[i] = r;
        cursor[i]    = r;
        dinv[i]      = rsqrtf((float)deg[i]);
    } else if (i == N_NODES) {
        row_start[N_NODES] = E_TOT;
    }
}

// ---- CSR fill: real edges + self-loops; packed {src, norm} per edge ----
__global__ __launch_bounds__(256) void k_fill(const int* __restrict__ src, const int* __restrict__ dst,
                                              const float* __restrict__ dinv, int* __restrict__ cursor,
                                              int2* __restrict__ csr_pack) {
    int e = blockIdx.x * 256 + threadIdx.x;
    if (e < N_EDGES) {
        int s = src[e], d = dst[e];
        int pos = atomicAdd(&cursor[d], 1);
        float nw = dinv[s] * dinv[d];
        csr_pack[pos] = make_int2(s, __float_as_int(nw));
    } else if (e < E_TOT) {
        int i = e - N_EDGES;
        int pos = atomicAdd(&cursor[i], 1);
        float di = dinv[i];
        csr_pack[pos] = make_int2(i, __float_as_int(di * di));
    }
}

// ---- fp32 GEMM: Y[M,128] = X[M,128] @ W[128,128]  (no bias; bias added post-agg) ----
__global__ __launch_bounds__(256) void k_gemm(const float* __restrict__ X,
                                              const float* __restrict__ W,
                                              float* __restrict__ Y) {
    __shared__ float xs[64][DIM];
    int tid  = threadIdx.x;
    int row0 = blockIdx.x * 64;
#pragma unroll
    for (int i = 0; i < 8; ++i) {
        int idx = tid + 256 * i;          // 0..2047 float4 slots
        int r = idx >> 5, c4 = idx & 31;
        int gr = row0 + r;
        float4 v = make_float4(0.f, 0.f, 0.f, 0.f);
        if (gr < N_NODES) v = ((const float4*)(X + (size_t)gr * DIM))[c4];
        ((float4*)(&xs[r][0]))[c4] = v;
    }
    __syncthreads();
    int tx = tid & 31;     // col group: cols 4*tx..4*tx+3
    int ty = tid >> 5;     // row group: rows 8*ty..8*ty+7
    float acc[8][4] = {};
    const float4* Wp = (const float4*)W + tx;     // row k at Wp[k*32]
#pragma unroll 4
    for (int k = 0; k < DIM; ++k) {
        float4 w = Wp[k * 32];
#pragma unroll
        for (int i = 0; i < 8; ++i) {
            float xv = xs[ty * 8 + i][k];         // wave-broadcast LDS read
            acc[i][0] = fmaf(xv, w.x, acc[i][0]);
            acc[i][1] = fmaf(xv, w.y, acc[i][1]);
            acc[i][2] = fmaf(xv, w.z, acc[i][2]);
            acc[i][3] = fmaf(xv, w.w, acc[i][3]);
        }
    }
#pragma unroll
    for (int i = 0; i < 8; ++i) {
        int gr = row0 + ty * 8 + i;
        if (gr < N_NODES)
            ((float4*)(Y + (size_t)gr * DIM))[tx] =
                make_float4(acc[i][0], acc[i][1], acc[i][2], acc[i][3]);
    }
}

// ---- gather-aggregate core: half-wave (32 lanes x float4) per node, 4-deep unroll ----
// One global_load_dwordx4 fetches rows for TWO nodes (one per half-wave); 8 row-loads
// in flight per wave vs 1 in the serial version. Masked tail via w=0 / s=0.
__device__ __forceinline__ float4 agg_node(const float4* __restrict__ H4,
                                           const int2* __restrict__ pack,
                                           int e0, int e1, int lane) {
    float4 a0 = {0,0,0,0}, a1 = {0,0,0,0}, a2 = {0,0,0,0}, a3 = {0,0,0,0};
    for (int e = e0; e < e1; e += 4) {
        int2 p0 = pack[e];
        int2 p1 = (e + 1 < e1) ? pack[e + 1] : make_int2(0, 0);
        int2 p2 = (e + 2 < e1) ? pack[e + 2] : make_int2(0, 0);
        int2 p3 = (e + 3 < e1) ? pack[e + 3] : make_int2(0, 0);
        float4 v0 = H4[(size_t)p0.x * 32 + lane];
        float4 v1 = H4[(size_t)p1.x * 32 + lane];
        float4 v2 = H4[(size_t)p2.x * 32 + lane];
        float4 v3 = H4[(size_t)p3.x * 32 + lane];
        float w0 = __int_as_float(p0.y), w1 = __int_as_float(p1.y);
        float w2 = __int_as_float(p2.y), w3 = __int_as_float(p3.y);
        a0.x = fmaf(w0, v0.x, a0.x); a0.y = fmaf(w0, v0.y, a0.y);
        a0.z = fmaf(w0, v0.z, a0.z); a0.w = fmaf(w0, v0.w, a0.w);
        a1.x = fmaf(w1, v1.x, a1.x); a1.y = fmaf(w1, v1.y, a1.y);
        a1.z = fmaf(w1, v1.z, a1.z); a1.w = fmaf(w1, v1.w, a1.w);
        a2.x = fmaf(w2, v2.x, a2.x); a2.y = fmaf(w2, v2.y, a2.y);
        a2.z = fmaf(w2, v2.z, a2.z); a2.w = fmaf(w2, v2.w, a2.w);
        a3.x = fmaf(w3, v3.x, a3.x); a3.y = fmaf(w3, v3.y, a3.y);
        a3.z = fmaf(w3, v3.z, a3.z); a3.w = fmaf(w3, v3.w, a3.w);
    }
    return make_float4(a0.x + a1.x + a2.x + a3.x,
                       a0.y + a1.y + a2.y + a3.y,
                       a0.z + a1.z + a2.z + a3.z,
                       a0.w + a1.w + a2.w + a3.w);
}

// relu(agg + bias) -> Out   (used for both layers; pooling is a separate kernel)
__global__ __launch_bounds__(256) void k_agg_store(const float* __restrict__ H,
                                                   const int2* __restrict__ pack,
                                                   const int* __restrict__ row_start,
                                                   const float* __restrict__ bias,
                                                   float* __restrict__ Out) {
    int node = blockIdx.x * 8 + (threadIdx.x >> 5);
    int lane = threadIdx.x & 31;
    if (node >= N_NODES) return;
    int e0 = row_start[node], e1 = row_start[node + 1];
    float4 acc = agg_node((const float4*)H, pack, e0, e1, lane);
    float4 b = ((const float4*)bias)[lane];
    float4 o = make_float4(fmaxf(acc.x + b.x, 0.f), fmaxf(acc.y + b.y, 0.f),
                           fmaxf(acc.z + b.z, 0.f), fmaxf(acc.w + b.w, 0.f));
    ((float4*)Out)[(size_t)node * 32 + lane] = o;
}

// ---- global add pool over sorted batch: register run-length + atomic flush ----
// 128 threads = one dim each; block owns POOL_CHUNK consecutive nodes; batch is
// sorted so boundaries are rare (~63 total) -> ~(blocks+63)*128 atomics over
// 8192 addresses. This was never in R1's top-5 (cheap); R2's per-lane atomic
// fusion (6.4M atomics) was 300us -- do NOT refuse this into the agg kernel.
__global__ __launch_bounds__(128) void k_pool(const float* __restrict__ H,
                                              const int* __restrict__ batch,
                                              float* __restrict__ pooled) {
    int dim   = threadIdx.x;
    int start = blockIdx.x * POOL_CHUNK;
    if (start >= N_NODES) return;
    int end = min(start + POOL_CHUNK, N_NODES);
    float acc = 0.f;
    int cb = batch[start];
    for (int i = start; i < end; ++i) {
        int b = batch[i];
        if (b != cb) {
            atomicAdd(&pooled[cb * DIM + dim], acc);
            acc = 0.f; cb = b;
        }
        acc += H[(size_t)i * DIM + dim];
    }
    atomicAdd(&pooled[cb * DIM + dim], acc);
}

// ---- head: logits = pooled @ Wh + bh ; log_softmax per graph ----
__global__ __launch_bounds__(64) void k_head(const float* __restrict__ pooled,
                                             const float* __restrict__ Wh,
                                             const float* __restrict__ bh,
                                             float* __restrict__ out) {
    int g = blockIdx.x;
    int lane = threadIdx.x;
    int c = lane & 31;
    const float* p = pooled + g * DIM;
    float lg = bh[c];
#pragma unroll 8
    for (int k = 0; k < DIM; ++k) lg = fmaf(p[k], Wh[k * DOUT + c], lg);
    float m = lg;
    for (int off = 16; off >= 1; off >>= 1) m = fmaxf(m, __shfl_xor(m, off, 32));
    float ex = expf(lg - m);
    float s = ex;
    for (int off = 16; off >= 1; off >>= 1) s += __shfl_xor(s, off, 32);
    if (lane < 32) out[g * DOUT + c] = lg - m - logf(s);
}

extern "C" void kernel_launch(void* const* d_in, const int* in_sizes, int n_in,
                              void* d_out, int out_size, void* d_ws, size_t ws_size,
                              hipStream_t stream) {
    const float* x     = (const float*)d_in[0];
    const int*   ei    = (const int*)d_in[1];
    const int*   batch = (const int*)d_in[2];
    const float* W1    = (const float*)d_in[3];
    const float* b1    = (const float*)d_in[4];
    const float* W2    = (const float*)d_in[5];
    const float* b2    = (const float*)d_in[6];
    const float* Wh    = (const float*)d_in[7];
    const float* bh    = (const float*)d_in[8];
    float* out = (float*)d_out;
    const int* src = ei;
    const int* dst = ei + N_EDGES;

    char* ws = (char*)d_ws;
    size_t off = 0;
    auto alloc = [&](size_t bytes) {
        void* p = ws + off;
        off += (bytes + 255) & ~(size_t)255;
        return p;
    };
    float* bufA      = (float*)alloc((size_t)N_NODES * DIM * 4);   // 25.6 MB
    float* bufB      = (float*)alloc((size_t)N_NODES * DIM * 4);   // 25.6 MB
    int*   deg       = (int*)  alloc((size_t)N_NODES * 4);
    float* dinv      = (float*)alloc((size_t)N_NODES * 4);
    int*   row_start = (int*)  alloc((size_t)(N_NODES + 1) * 4);
    int*   cursor    = (int*)  alloc((size_t)N_NODES * 4);
    int2*  csr_pack  = (int2*) alloc((size_t)E_TOT * 8);
    float* pooled    = (float*)alloc((size_t)NGRAPH * DIM * 4);
    int*   bsum      = (int*)  alloc(128 * 4);
    int*   boff      = (int*)  alloc(128 * 4);
    (void)ws_size; (void)in_sizes; (void)n_in; (void)out_size;

    k_init      <<<(N_NODES + 255) / 256, 256, 0, stream>>>(deg, pooled);
    k_count_deg <<<(N_EDGES + 255) / 256, 256, 0, stream>>>(dst, deg);
    k_scan_block<<<98, 512, 0, stream>>>(deg, row_start, bsum);
    k_scan_bsum <<<1, 128, 0, stream>>>(bsum, boff);
    k_finalize  <<<(N_NODES + 256) / 256, 256, 0, stream>>>(deg, boff, row_start, cursor, dinv);
    k_fill      <<<(E_TOT + 255) / 256, 256, 0, stream>>>(src, dst, dinv, cursor, csr_pack);

    k_gemm     <<<(N_NODES + 63) / 64, 256, 0, stream>>>(x, W1, bufA);
    k_agg_store<<<(N_NODES + 7) / 8, 256, 0, stream>>>(bufA, csr_pack, row_start, b1, bufB);
    k_gemm     <<<(N_NODES + 63) / 64, 256, 0, stream>>>(bufB, W2, bufA);
    k_agg_store<<<(N_NODES + 7) / 8, 256, 0, stream>>>(bufA, csr_pack, row_start, b2, bufB);

    k_pool<<<(N_NODES + POOL_CHUNK - 1) / POOL_CHUNK, 128, 0, stream>>>(bufB, batch, pooled);
    k_head<<<NGRAPH, 64, 0, stream>>>(pooled, Wh, bh, out);
}

// Round 4
// 303.124 us; speedup vs baseline: 1.8183x; 1.0830x over previous
//
#include <hip/hip_runtime.h>
#include <math.h>

#define N_NODES 50000
#define N_EDGES 640000
#define DIM     128
#define NGRAPH  64
#define DOUT    32
#define E_TOT   (N_EDGES + N_NODES)
#define POOL_CHUNK 32

typedef unsigned short u16;

// fp32 -> bf16 round-to-nearest-even
__device__ __forceinline__ u16 f2bf(float f) {
    unsigned u = __float_as_uint(f);
    return (u16)((u + 0x7FFFu + ((u >> 16) & 1u)) >> 16);
}
__device__ __forceinline__ float bf2f(u16 h) {
    return __uint_as_float(((unsigned)h) << 16);
}

// ---- degree count (deg starts at 0 via memsetAsync; true degree = deg+1 w/ self-loop) ----
__global__ __launch_bounds__(256) void k_count_deg(const int* __restrict__ dst, int* __restrict__ deg) {
    int e = blockIdx.x * 256 + threadIdx.x;
    if (e < N_EDGES) atomicAdd(&deg[dst[e]], 1);
}

// ---- block-level exclusive scan of (deg+1) -> row_start + per-block totals ----
__global__ __launch_bounds__(512) void k_scan_block(const int* __restrict__ deg,
                                                    int* __restrict__ row_start,
                                                    int* __restrict__ bsum) {
    __shared__ int sd[512];
    int t = threadIdx.x;
    int i = blockIdx.x * 512 + t;
    int v = (i < N_NODES) ? (deg[i] + 1) : 0;
    int sum = v;
    sd[t] = v; __syncthreads();
    for (int off = 1; off < 512; off <<= 1) {
        int o = (t >= off) ? sd[t - off] : 0;
        __syncthreads();
        sum += o; sd[t] = sum;
        __syncthreads();
    }
    if (i < N_NODES) row_start[i] = sum - v;       // exclusive within block
    if (t == 511) bsum[blockIdx.x] = sum;          // block total
}

// ---- finalize: scan the 98 block sums in-LDS (redundant per block, trivial), apply,
//      init cursor, compute dinv = rsqrt(deg+1) ----
__global__ __launch_bounds__(256) void k_finalize(const int* __restrict__ deg,
                                                  const int* __restrict__ bsum,
                                                  int* __restrict__ row_start,
                                                  int* __restrict__ cursor,
                                                  float* __restrict__ dinv) {
    __shared__ int sb[128];
    int t = threadIdx.x;
    if (t < 128) sb[t] = (t < 98) ? bsum[t] : 0;
    __syncthreads();
    for (int off = 1; off < 128; off <<= 1) {
        int v = 0;
        if (t < 128 && t >= off) v = sb[t - off];
        __syncthreads();
        if (t < 128) sb[t] += v;                   // inclusive scan
        __syncthreads();
    }
    int i = blockIdx.x * 256 + t;
    if (i < N_NODES) {
        int b9 = i >> 9;
        int boff = (b9 == 0) ? 0 : sb[b9 - 1];
        int r = row_start[i] + boff;
        row_start[i] = r;
        cursor[i]    = r;
        dinv[i]      = rsqrtf((float)(deg[i] + 1));
    } else if (i == N_NODES) {
        row_start[N_NODES] = E_TOT;
    }
}

// ---- CSR fill: real edges + self-loops; packed {src, norm} per edge ----
__global__ __launch_bounds__(256) void k_fill(const int* __restrict__ src, const int* __restrict__ dst,
                                              const float* __restrict__ dinv, int* __restrict__ cursor,
                                              int2* __restrict__ csr_pack) {
    int e = blockIdx.x * 256 + threadIdx.x;
    if (e < N_EDGES) {
        int s = src[e], d = dst[e];
        int pos = atomicAdd(&cursor[d], 1);
        float nw = dinv[s] * dinv[d];
        csr_pack[pos] = make_int2(s, __float_as_int(nw));
    } else if (e < E_TOT) {
        int i = e - N_EDGES;
        int pos = atomicAdd(&cursor[i], 1);
        float di = dinv[i];
        csr_pack[pos] = make_int2(i, __float_as_int(di * di));
    }
}

// ---- GEMM: Y[M,128](bf16) = X[M,128] @ W[128,128], fp32 accumulate ----
// BF16IN: X is bf16 (unpacked to fp32 in LDS); else X is fp32.
template <bool BF16IN>
__global__ __launch_bounds__(256) void k_gemm(const void* __restrict__ Xv,
                                              const float* __restrict__ W,
                                              u16* __restrict__ Y) {
    __shared__ float xs[64][DIM];
    int tid  = threadIdx.x;
    int row0 = blockIdx.x * 64;
#pragma unroll
    for (int i = 0; i < 8; ++i) {
        int idx = tid + 256 * i;          // 2048 float4-slots (64 rows x 32)
        int r = idx >> 5, c4 = idx & 31;
        int gr = row0 + r;
        float4 v = make_float4(0.f, 0.f, 0.f, 0.f);
        if (gr < N_NODES) {
            if (BF16IN) {
                ushort4 h = ((const ushort4*)Xv)[(size_t)gr * 32 + c4];
                v = make_float4(bf2f(h.x), bf2f(h.y), bf2f(h.z), bf2f(h.w));
            } else {
                v = ((const float4*)Xv)[(size_t)gr * 32 + c4];
            }
        }
        ((float4*)(&xs[r][0]))[c4] = v;
    }
    __syncthreads();
    int tx = tid & 31;     // cols 4*tx..4*tx+3
    int ty = tid >> 5;     // rows 8*ty..8*ty+7
    float acc[8][4] = {};
    const float4* Wp = (const float4*)W + tx;
#pragma unroll 4
    for (int k = 0; k < DIM; ++k) {
        float4 w = Wp[k * 32];
#pragma unroll
        for (int i = 0; i < 8; ++i) {
            float xv = xs[ty * 8 + i][k];
            acc[i][0] = fmaf(xv, w.x, acc[i][0]);
            acc[i][1] = fmaf(xv, w.y, acc[i][1]);
            acc[i][2] = fmaf(xv, w.z, acc[i][2]);
            acc[i][3] = fmaf(xv, w.w, acc[i][3]);
        }
    }
#pragma unroll
    for (int i = 0; i < 8; ++i) {
        int gr = row0 + ty * 8 + i;
        if (gr < N_NODES) {
            ushort4 o;
            o.x = f2bf(acc[i][0]); o.y = f2bf(acc[i][1]);
            o.z = f2bf(acc[i][2]); o.w = f2bf(acc[i][3]);
            ((ushort4*)Y)[(size_t)gr * 32 + tx] = o;
        }
    }
}

// ---- gather-aggregate core (bf16 rows): half-wave (32 lanes x ushort4) per node,
//      4-deep unroll -> 8 independent 256B row reads in flight per wave. fp32 accum. ----
__device__ __forceinline__ float4 agg_node(const ushort4* __restrict__ H4,
                                           const int2* __restrict__ pack,
                                           int e0, int e1, int lane) {
    float4 a0 = {0,0,0,0}, a1 = {0,0,0,0}, a2 = {0,0,0,0}, a3 = {0,0,0,0};
    for (int e = e0; e < e1; e += 4) {
        int2 p0 = pack[e];
        int2 p1 = (e + 1 < e1) ? pack[e + 1] : make_int2(0, 0);
        int2 p2 = (e + 2 < e1) ? pack[e + 2] : make_int2(0, 0);
        int2 p3 = (e + 3 < e1) ? pack[e + 3] : make_int2(0, 0);
        ushort4 v0 = H4[(size_t)p0.x * 32 + lane];
        ushort4 v1 = H4[(size_t)p1.x * 32 + lane];
        ushort4 v2 = H4[(size_t)p2.x * 32 + lane];
        ushort4 v3 = H4[(size_t)p3.x * 32 + lane];
        float w0 = __int_as_float(p0.y), w1 = __int_as_float(p1.y);
        float w2 = __int_as_float(p2.y), w3 = __int_as_float(p3.y);
        a0.x = fmaf(w0, bf2f(v0.x), a0.x); a0.y = fmaf(w0, bf2f(v0.y), a0.y);
        a0.z = fmaf(w0, bf2f(v0.z), a0.z); a0.w = fmaf(w0, bf2f(v0.w), a0.w);
        a1.x = fmaf(w1, bf2f(v1.x), a1.x); a1.y = fmaf(w1, bf2f(v1.y), a1.y);
        a1.z = fmaf(w1, bf2f(v1.z), a1.z); a1.w = fmaf(w1, bf2f(v1.w), a1.w);
        a2.x = fmaf(w2, bf2f(v2.x), a2.x); a2.y = fmaf(w2, bf2f(v2.y), a2.y);
        a2.z = fmaf(w2, bf2f(v2.z), a2.z); a2.w = fmaf(w2, bf2f(v2.w), a2.w);
        a3.x = fmaf(w3, bf2f(v3.x), a3.x); a3.y = fmaf(w3, bf2f(v3.y), a3.y);
        a3.z = fmaf(w3, bf2f(v3.z), a3.z); a3.w = fmaf(w3, bf2f(v3.w), a3.w);
    }
    return make_float4(a0.x + a1.x + a2.x + a3.x,
                       a0.y + a1.y + a2.y + a3.y,
                       a0.z + a1.z + a2.z + a3.z,
                       a0.w + a1.w + a2.w + a3.w);
}

// relu(agg + bias) -> Out (bf16)
__global__ __launch_bounds__(256) void k_agg_store(const u16* __restrict__ H,
                                                   const int2* __restrict__ pack,
                                                   const int* __restrict__ row_start,
                                                   const float* __restrict__ bias,
                                                   u16* __restrict__ Out) {
    int node = blockIdx.x * 8 + (threadIdx.x >> 5);
    int lane = threadIdx.x & 31;
    if (node >= N_NODES) return;
    int e0 = row_start[node], e1 = row_start[node + 1];
    float4 acc = agg_node((const ushort4*)H, pack, e0, e1, lane);
    float4 b = ((const float4*)bias)[lane];
    ushort4 o;
    o.x = f2bf(fmaxf(acc.x + b.x, 0.f));
    o.y = f2bf(fmaxf(acc.y + b.y, 0.f));
    o.z = f2bf(fmaxf(acc.z + b.z, 0.f));
    o.w = f2bf(fmaxf(acc.w + b.w, 0.f));
    ((ushort4*)Out)[(size_t)node * 32 + lane] = o;
}

// ---- global add pool over sorted batch (bf16 input): register run-length + atomic flush ----
// ~(blocks + 63) * 128 atomics over 8192 addresses. (R2 lesson: do NOT fuse per-lane
// atomics into the agg kernel -- 6.4M atomics onto 8192 addrs was 300us.)
__global__ __launch_bounds__(128) void k_pool(const u16* __restrict__ H,
                                              const int* __restrict__ batch,
                                              float* __restrict__ pooled) {
    int dim   = threadIdx.x;
    int start = blockIdx.x * POOL_CHUNK;
    if (start >= N_NODES) return;
    int end = min(start + POOL_CHUNK, N_NODES);
    float acc = 0.f;
    int cb = batch[start];
    for (int i = start; i < end; ++i) {
        int b = batch[i];
        if (b != cb) {
            atomicAdd(&pooled[cb * DIM + dim], acc);
            acc = 0.f; cb = b;
        }
        acc += bf2f(H[(size_t)i * DIM + dim]);
    }
    atomicAdd(&pooled[cb * DIM + dim], acc);
}

// ---- head: logits = pooled @ Wh + bh ; log_softmax per graph ----
__global__ __launch_bounds__(64) void k_head(const float* __restrict__ pooled,
                                             const float* __restrict__ Wh,
                                             const float* __restrict__ bh,
                                             float* __restrict__ out) {
    int g = blockIdx.x;
    int lane = threadIdx.x;
    int c = lane & 31;
    const float* p = pooled + g * DIM;
    float lg = bh[c];
#pragma unroll 8
    for (int k = 0; k < DIM; ++k) lg = fmaf(p[k], Wh[k * DOUT + c], lg);
    float m = lg;
    for (int off = 16; off >= 1; off >>= 1) m = fmaxf(m, __shfl_xor(m, off, 32));
    float ex = expf(lg - m);
    float s = ex;
    for (int off = 16; off >= 1; off >>= 1) s += __shfl_xor(s, off, 32);
    if (lane < 32) out[g * DOUT + c] = lg - m - logf(s);
}

extern "C" void kernel_launch(void* const* d_in, const int* in_sizes, int n_in,
                              void* d_out, int out_size, void* d_ws, size_t ws_size,
                              hipStream_t stream) {
    const float* x     = (const float*)d_in[0];
    const int*   ei    = (const int*)d_in[1];
    const int*   batch = (const int*)d_in[2];
    const float* W1    = (const float*)d_in[3];
    const float* b1    = (const float*)d_in[4];
    const float* W2    = (const float*)d_in[5];
    const float* b2    = (const float*)d_in[6];
    const float* Wh    = (const float*)d_in[7];
    const float* bh    = (const float*)d_in[8];
    float* out = (float*)d_out;
    const int* src = ei;
    const int* dst = ei + N_EDGES;

    char* ws = (char*)d_ws;
    size_t off = 0;
    auto alloc = [&](size_t bytes) {
        void* p = ws + off;
        off += (bytes + 255) & ~(size_t)255;
        return p;
    };
    u16*   bufA      = (u16*)  alloc((size_t)N_NODES * DIM * 2);   // 12.8 MB bf16
    u16*   bufB      = (u16*)  alloc((size_t)N_NODES * DIM * 2);   // 12.8 MB bf16
    int*   deg       = (int*)  alloc((size_t)N_NODES * 4);
    float* dinv      = (float*)alloc((size_t)N_NODES * 4);
    int*   row_start = (int*)  alloc((size_t)(N_NODES + 1) * 4);
    int*   cursor    = (int*)  alloc((size_t)N_NODES * 4);
    int2*  csr_pack  = (int2*) alloc((size_t)E_TOT * 8);
    float* pooled    = (float*)alloc((size_t)NGRAPH * DIM * 4);
    int*   bsum      = (int*)  alloc(128 * 4);
    (void)ws_size; (void)in_sizes; (void)n_in; (void)out_size;

    hipMemsetAsync(deg, 0, (size_t)N_NODES * 4, stream);
    hipMemsetAsync(pooled, 0, (size_t)NGRAPH * DIM * 4, stream);

    k_count_deg <<<(N_EDGES + 255) / 256, 256, 0, stream>>>(dst, deg);
    k_scan_block<<<98, 512, 0, stream>>>(deg, row_start, bsum);
    k_finalize  <<<(N_NODES + 256) / 256, 256, 0, stream>>>(deg, bsum, row_start, cursor, dinv);
    k_fill      <<<(E_TOT + 255) / 256, 256, 0, stream>>>(src, dst, dinv, cursor, csr_pack);

    k_gemm<false><<<(N_NODES + 63) / 64, 256, 0, stream>>>(x, W1, bufA);
    k_agg_store  <<<(N_NODES + 7) / 8, 256, 0, stream>>>(bufA, csr_pack, row_start, b1, bufB);
    k_gemm<true> <<<(N_NODES + 63) / 64, 256, 0, stream>>>(bufB, W2, bufA);
    k_agg_store  <<<(N_NODES + 7) / 8, 256, 0, stream>>>(bufA, csr_pack, row_start, b2, bufB);

    k_pool<<<(N_NODES + POOL_CHUNK - 1) / POOL_CHUNK, 128, 0, stream>>>(bufB, batch, pooled);
    k_head<<<NGRAPH, 64, 0, stream>>>(pooled, Wh, bh, out);
}

// Round 5
// 271.244 us; speedup vs baseline: 2.0320x; 1.1175x over previous
//
#include <hip/hip_runtime.h>
#include <math.h>

#define N_NODES 50000
#define N_EDGES 640000
#define DIM     128
#define NGRAPH  64
#define DOUT    32
#define POOL_CHUNK 32

typedef unsigned short u16;
typedef __attribute__((ext_vector_type(8))) short bf16x8;
typedef __attribute__((ext_vector_type(4))) float f32x4;

// fp32 -> bf16 round-to-nearest-even
__device__ __forceinline__ u16 f2bf(float f) {
    unsigned u = __float_as_uint(f);
    return (u16)((u + 0x7FFFu + ((u >> 16) & 1u)) >> 16);
}
__device__ __forceinline__ float bf2f(u16 h) {
    return __uint_as_float(((unsigned)h) << 16);
}

// ---- in-degree count (deg zeroed via memsetAsync; normalization uses deg+1) ----
__global__ __launch_bounds__(256) void k_count_deg(const int* __restrict__ dst, int* __restrict__ deg) {
    int e = blockIdx.x * 256 + threadIdx.x;
    if (e < N_EDGES) atomicAdd(&deg[dst[e]], 1);
}

// ---- block-level exclusive scan of deg (in-degree; self-loops NOT in CSR) ----
__global__ __launch_bounds__(512) void k_scan_block(const int* __restrict__ deg,
                                                    int* __restrict__ row_start,
                                                    int* __restrict__ bsum) {
    __shared__ int sd[512];
    int t = threadIdx.x;
    int i = blockIdx.x * 512 + t;
    int v = (i < N_NODES) ? deg[i] : 0;
    int sum = v;
    sd[t] = v; __syncthreads();
    for (int off = 1; off < 512; off <<= 1) {
        int o = (t >= off) ? sd[t - off] : 0;
        __syncthreads();
        sum += o; sd[t] = sum;
        __syncthreads();
    }
    if (i < N_NODES) row_start[i] = sum - v;
    if (t == 511) bsum[blockIdx.x] = sum;
}

// ---- finalize: in-LDS scan of 98 block sums, apply offset, init cursor, dinv ----
__global__ __launch_bounds__(256) void k_finalize(const int* __restrict__ deg,
                                                  const int* __restrict__ bsum,
                                                  int* __restrict__ row_start,
                                                  int* __restrict__ cursor,
                                                  float* __restrict__ dinv) {
    __shared__ int sb[128];
    int t = threadIdx.x;
    if (t < 128) sb[t] = (t < 98) ? bsum[t] : 0;
    __syncthreads();
    for (int off = 1; off < 128; off <<= 1) {
        int v = 0;
        if (t < 128 && t >= off) v = sb[t - off];
        __syncthreads();
        if (t < 128) sb[t] += v;
        __syncthreads();
    }
    int i = blockIdx.x * 256 + t;
    if (i < N_NODES) {
        int b9 = i >> 9;
        int boff = (b9 == 0) ? 0 : sb[b9 - 1];
        int r = row_start[i] + boff;
        row_start[i] = r;
        cursor[i]    = r;
        dinv[i]      = rsqrtf((float)(deg[i] + 1));
    } else if (i == N_NODES) {
        row_start[N_NODES] = N_EDGES;
    }
}

// ---- CSR fill: 4B src index only (norm factored out; self-loops analytic) ----
__global__ __launch_bounds__(256) void k_fill(const int* __restrict__ src, const int* __restrict__ dst,
                                              int* __restrict__ cursor, int* __restrict__ csr_src) {
    int e = blockIdx.x * 256 + threadIdx.x;
    if (e < N_EDGES) {
        int pos = atomicAdd(&cursor[dst[e]], 1);
        csr_src[pos] = src[e];
    }
}

// ---- GEMM1 (fp32 vector): Y(bf16) = dinv[row] * (X @ W) ----
__global__ __launch_bounds__(256) void k_gemm1(const float* __restrict__ X,
                                               const float* __restrict__ W,
                                               const float* __restrict__ dinv,
                                               u16* __restrict__ Y) {
    __shared__ float xs[64][DIM];
    int tid  = threadIdx.x;
    int row0 = blockIdx.x * 64;
#pragma unroll
    for (int i = 0; i < 8; ++i) {
        int idx = tid + 256 * i;
        int r = idx >> 5, c4 = idx & 31;
        int gr = row0 + r;
        float4 v = make_float4(0.f, 0.f, 0.f, 0.f);
        if (gr < N_NODES) v = ((const float4*)X)[(size_t)gr * 32 + c4];
        ((float4*)(&xs[r][0]))[c4] = v;
    }
    __syncthreads();
    int tx = tid & 31;
    int ty = tid >> 5;
    float acc[8][4] = {};
    const float4* Wp = (const float4*)W + tx;
#pragma unroll 4
    for (int k = 0; k < DIM; ++k) {
        float4 w = Wp[k * 32];
#pragma unroll
        for (int i = 0; i < 8; ++i) {
            float xv = xs[ty * 8 + i][k];
            acc[i][0] = fmaf(xv, w.x, acc[i][0]);
            acc[i][1] = fmaf(xv, w.y, acc[i][1]);
            acc[i][2] = fmaf(xv, w.z, acc[i][2]);
            acc[i][3] = fmaf(xv, w.w, acc[i][3]);
        }
    }
#pragma unroll
    for (int i = 0; i < 8; ++i) {
        int gr = row0 + ty * 8 + i;
        if (gr < N_NODES) {
            float di = dinv[gr];
            ushort4 o;
            o.x = f2bf(acc[i][0] * di); o.y = f2bf(acc[i][1] * di);
            o.z = f2bf(acc[i][2] * di); o.w = f2bf(acc[i][3] * di);
            ((ushort4*)Y)[(size_t)gr * 32 + tx] = o;
        }
    }
}

// ---- W2 -> bf16, pre-swizzled into MFMA B-fragment order ----
// B frag (16x16x32): lane holds B[k][n], n=lane&15, k=(lane>>4)*8+j.
// Ws[((nt*4+kc)*64 + lane)*8 + j] = bf16(W[(kc*32 + (lane>>4)*8 + j)*128 + nt*16 + (lane&15)])
__global__ __launch_bounds__(256) void k_cvtW(const float* __restrict__ W, u16* __restrict__ Ws) {
    int t = blockIdx.x * 256 + threadIdx.x;     // 16384 total
    int j    = t & 7;
    int lane = (t >> 3) & 63;
    int kc   = (t >> 9) & 3;
    int nt   = t >> 11;
    int k = kc * 32 + (lane >> 4) * 8 + j;
    int n = nt * 16 + (lane & 15);
    Ws[t] = f2bf(W[k * 128 + n]);
}

// ---- GEMM2 (bf16 MFMA): Y(bf16) = dinv[row] * (A @ W2), fp32 accumulate ----
// A layout (verified m120): A[m=lane&15][k=(lane>>4)*8+j]; C/D (verified m89):
// col=lane&15, row=(lane>>4)*4+reg. 4 waves/block, wave = 16 rows x 128 cols.
__global__ __launch_bounds__(256) void k_gemm2(const u16* __restrict__ A,
                                               const u16* __restrict__ Ws,
                                               const float* __restrict__ dinv,
                                               u16* __restrict__ Y) {
    int wv   = threadIdx.x >> 6;
    int lane = threadIdx.x & 63;
    int row0 = blockIdx.x * 64 + wv * 16;
    int m    = lane & 15;
    int quad = lane >> 4;
    int ar = min(row0 + m, N_NODES - 1);           // clamp: ws is padded, safe
    const u16* Arow = A + (size_t)ar * DIM;
    bf16x8 a[4];
#pragma unroll
    for (int kc = 0; kc < 4; ++kc)
        a[kc] = *(const bf16x8*)(Arow + kc * 32 + quad * 8);
    float di[4];
#pragma unroll
    for (int r = 0; r < 4; ++r) {
        int rr = row0 + quad * 4 + r;
        di[r] = (rr < N_NODES) ? dinv[rr] : 0.f;
    }
#pragma unroll
    for (int nt = 0; nt < 8; ++nt) {
        f32x4 acc = {0.f, 0.f, 0.f, 0.f};
#pragma unroll
        for (int kc = 0; kc < 4; ++kc) {
            bf16x8 b = *(const bf16x8*)(Ws + ((size_t)(nt * 4 + kc) * 64 + lane) * 8);
            acc = __builtin_amdgcn_mfma_f32_16x16x32_bf16(a[kc], b, acc, 0, 0, 0);
        }
        int col = nt * 16 + m;
#pragma unroll
        for (int r = 0; r < 4; ++r) {
            int rr = row0 + quad * 4 + r;
            if (rr < N_NODES) Y[(size_t)rr * DIM + col] = f2bf(acc[r] * di[r]);
        }
    }
}

// ---- gather-aggregate: out_i = relu(dinv_i*(sum_{in(i)} hs_j + hs_i) + b) ----
// Half-wave (32 lanes x ushort4) per node, 8-deep unroll -> 16 row-loads in
// flight per wave (R4 lesson: 256B rows made 4-deep latency-bound, not BW-bound).
// Tail: clamp index to last edge (L1-hot dup), weight 0/1 via fma.
__global__ __launch_bounds__(256) void k_agg(const u16* __restrict__ H,
                                             const int* __restrict__ csr_src,
                                             const int* __restrict__ row_start,
                                             const float* __restrict__ dinv,
                                             const float* __restrict__ bias,
                                             u16* __restrict__ Out) {
    int node = blockIdx.x * 8 + (threadIdx.x >> 5);
    int lane = threadIdx.x & 31;
    if (node >= N_NODES) return;
    int e0 = row_start[node], e1 = row_start[node + 1];
    const ushort4* H4 = (const ushort4*)H;
    ushort4 sv = H4[(size_t)node * 32 + lane];    // self term hs_i
    float4 ac0 = make_float4(bf2f(sv.x), bf2f(sv.y), bf2f(sv.z), bf2f(sv.w));
    float4 ac1 = {0,0,0,0}, ac2 = {0,0,0,0}, ac3 = {0,0,0,0};
    for (int e = e0; e < e1; e += 8) {
        int   idx[8];
        float w[8];
        ushort4 v[8];
#pragma unroll
        for (int u = 0; u < 8; ++u) {
            int eu = e + u;
            int ec = min(eu, e1 - 1);
            idx[u] = csr_src[ec];
            w[u]   = (eu < e1) ? 1.f : 0.f;
        }
#pragma unroll
        for (int u = 0; u < 8; ++u) v[u] = H4[(size_t)idx[u] * 32 + lane];
#pragma unroll
        for (int u = 0; u < 8; ++u) {
            float4* a = (u & 3) == 0 ? &ac0 : (u & 3) == 1 ? &ac1 : (u & 3) == 2 ? &ac2 : &ac3;
            a->x = fmaf(w[u], bf2f(v[u].x), a->x);
            a->y = fmaf(w[u], bf2f(v[u].y), a->y);
            a->z = fmaf(w[u], bf2f(v[u].z), a->z);
            a->w = fmaf(w[u], bf2f(v[u].w), a->w);
        }
    }
    float di = dinv[node];
    float4 b = ((const float4*)bias)[lane];
    ushort4 o;
    o.x = f2bf(fmaxf(di * (ac0.x + ac1.x + ac2.x + ac3.x) + b.x, 0.f));
    o.y = f2bf(fmaxf(di * (ac0.y + ac1.y + ac2.y + ac3.y) + b.y, 0.f));
    o.z = f2bf(fmaxf(di * (ac0.z + ac1.z + ac2.z + ac3.z) + b.z, 0.f));
    o.w = f2bf(fmaxf(di * (ac0.w + ac1.w + ac2.w + ac3.w) + b.w, 0.f));
    ((ushort4*)Out)[(size_t)node * 32 + lane] = o;
}

// ---- global add pool over sorted batch: register run-length + atomic flush ----
// (R2 lesson: never per-lane atomics into 8K addresses -- 300us.)
__global__ __launch_bounds__(128) void k_pool(const u16* __restrict__ H,
                                              const int* __restrict__ batch,
                                              float* __restrict__ pooled) {
    int dim   = threadIdx.x;
    int start = blockIdx.x * POOL_CHUNK;
    if (start >= N_NODES) return;
    int end = min(start + POOL_CHUNK, N_NODES);
    float acc = 0.f;
    int cb = batch[start];
    for (int i = start; i < end; ++i) {
        int b = batch[i];
        if (b != cb) {
            atomicAdd(&pooled[cb * DIM + dim], acc);
            acc = 0.f; cb = b;
        }
        acc += bf2f(H[(size_t)i * DIM + dim]);
    }
    atomicAdd(&pooled[cb * DIM + dim], acc);
}

// ---- head: logits = pooled @ Wh + bh ; log_softmax per graph ----
__global__ __launch_bounds__(64) void k_head(const float* __restrict__ pooled,
                                             const float* __restrict__ Wh,
                                             const float* __restrict__ bh,
                                             float* __restrict__ out) {
    int g = blockIdx.x;
    int lane = threadIdx.x;
    int c = lane & 31;
    const float* p = pooled + g * DIM;
    float lg = bh[c];
#pragma unroll 8
    for (int k = 0; k < DIM; ++k) lg = fmaf(p[k], Wh[k * DOUT + c], lg);
    float m = lg;
    for (int off = 16; off >= 1; off >>= 1) m = fmaxf(m, __shfl_xor(m, off, 32));
    float ex = expf(lg - m);
    float s = ex;
    for (int off = 16; off >= 1; off >>= 1) s += __shfl_xor(s, off, 32);
    if (lane < 32) out[g * DOUT + c] = lg - m - logf(s);
}

extern "C" void kernel_launch(void* const* d_in, const int* in_sizes, int n_in,
                              void* d_out, int out_size, void* d_ws, size_t ws_size,
                              hipStream_t stream) {
    const float* x     = (const float*)d_in[0];
    const int*   ei    = (const int*)d_in[1];
    const int*   batch = (const int*)d_in[2];
    const float* W1    = (const float*)d_in[3];
    const float* b1    = (const float*)d_in[4];
    const float* W2    = (const float*)d_in[5];
    const float* b2    = (const float*)d_in[6];
    const float* Wh    = (const float*)d_in[7];
    const float* bh    = (const float*)d_in[8];
    float* out = (float*)d_out;
    const int* src = ei;
    const int* dst = ei + N_EDGES;

    char* ws = (char*)d_ws;
    size_t off = 0;
    auto alloc = [&](size_t bytes) {
        void* p = ws + off;
        off += (bytes + 255) & ~(size_t)255;
        return p;
    };
    u16*   bufA      = (u16*)  alloc((size_t)N_NODES * DIM * 2);   // 12.8 MB bf16
    u16*   bufB      = (u16*)  alloc((size_t)N_NODES * DIM * 2);   // 12.8 MB bf16
    int*   deg       = (int*)  alloc((size_t)N_NODES * 4);
    float* dinv      = (float*)alloc((size_t)N_NODES * 4);
    int*   row_start = (int*)  alloc((size_t)(N_NODES + 1) * 4);
    int*   cursor    = (int*)  alloc((size_t)N_NODES * 4);
    int*   csr_src   = (int*)  alloc((size_t)N_EDGES * 4);
    u16*   W2s       = (u16*)  alloc((size_t)DIM * DIM * 2);
    float* pooled    = (float*)alloc((size_t)NGRAPH * DIM * 4);
    int*   bsum      = (int*)  alloc(128 * 4);
    (void)ws_size; (void)in_sizes; (void)n_in; (void)out_size;

    hipMemsetAsync(deg, 0, (size_t)N_NODES * 4, stream);
    hipMemsetAsync(pooled, 0, (size_t)NGRAPH * DIM * 4, stream);

    k_count_deg <<<(N_EDGES + 255) / 256, 256, 0, stream>>>(dst, deg);
    k_scan_block<<<98, 512, 0, stream>>>(deg, row_start, bsum);
    k_finalize  <<<(N_NODES + 256) / 256, 256, 0, stream>>>(deg, bsum, row_start, cursor, dinv);
    k_fill      <<<(N_EDGES + 255) / 256, 256, 0, stream>>>(src, dst, cursor, csr_src);
    k_cvtW      <<<64, 256, 0, stream>>>(W2, W2s);

    k_gemm1<<<(N_NODES + 63) / 64, 256, 0, stream>>>(x, W1, dinv, bufA);
    k_agg  <<<(N_NODES + 7) / 8, 256, 0, stream>>>(bufA, csr_src, row_start, dinv, b1, bufB);
    k_gemm2<<<(N_NODES + 63) / 64, 256, 0, stream>>>(bufB, W2s, dinv, bufA);
    k_agg  <<<(N_NODES + 7) / 8, 256, 0, stream>>>(bufA, csr_src, row_start, dinv, b2, bufB);

    k_pool<<<(N_NODES + POOL_CHUNK - 1) / POOL_CHUNK, 128, 0, stream>>>(bufB, batch, pooled);
    k_head<<<NGRAPH, 64, 0, stream>>>(pooled, Wh, bh, out);
}